// Round 9
// baseline (928.603 us; speedup 1.0000x reference)
//
#include <hip/hip_runtime.h>
#include <hip/hip_bf16.h>

#define Bb 128
#define Tt 1024
#define Nn 128
#define Ss 256
#define NEGF (-1e30f)
#define D9 9.0f   // fixed log-domain shift per step; absorbed as D9*(len-1) at the end

typedef __attribute__((ext_vector_type(8))) short short8;  // 8 bf16 = 4 VGPRs (MFMA A/B frag)
typedef __attribute__((ext_vector_type(4))) float f32x4;   // MFMA C/D frag

__device__ __forceinline__ short bf16b(float f) {
    __hip_bfloat16 h = __float2bfloat16(f);
    return *reinterpret_cast<short*>(&h);
}
__device__ __forceinline__ unsigned int pk2(float lo, float hi) {
    return ((unsigned int)(unsigned short)bf16b(lo)) |
           ((unsigned int)(unsigned short)bf16b(hi) << 16);
}
__device__ __forceinline__ float bflo(unsigned int d) { return __uint_as_float(d << 16); }
__device__ __forceinline__ float bfhi(unsigned int d) { return __uint_as_float(d & 0xFFFF0000u); }

// Pre-kernel (path A): w[b][t][j] = exp(x - D9) as bf16. 96 MB traffic ~ 15 us.
__global__ __launch_bounds__(256) void wexp_kernel(const float* __restrict__ x,
                                                   unsigned short* __restrict__ w) {
    size_t i = ((size_t)blockIdx.x * 256 + threadIdx.x) * 8;
    float4 a = *(const float4*)(x + i);
    float4 b = *(const float4*)(x + i + 4);
    int4 o;
    o.x = (int)pk2(__expf(a.x - D9), __expf(a.y - D9));
    o.y = (int)pk2(__expf(a.z - D9), __expf(a.w - D9));
    o.z = (int)pk2(__expf(b.x - D9), __expf(b.y - D9));
    o.w = (int)pk2(__expf(b.z - D9), __expf(b.w - D9));
    *(int4*)(w + i) = o;
}

// ---------------- FCC: ONE WAVE per 16-batch group, ZERO barriers ----------------
// E row-permuted: D-tile (mt,quad,r) holds true row j = 32*quad + 4*mt + r, so each
// lane's 32 outputs are contiguous 64B -> 4x ds_write_b128. B-read: ut[g][32kc+8quad].
// Freeze replaced by "ones" sum-tile + snapshot (S,C) at t==len (runs t=1..1024).
template<bool PRE>
__device__ __forceinline__ void fcc_wave(
    const float* __restrict__ trans, const float* __restrict__ x,
    const unsigned short* __restrict__ w, const int* __restrict__ ilen,
    float* __restrict__ fcc_out, int group, short* lds, int lane)
{
    const int g    = lane & 15;
    const int quad = lane >> 4;
    const int b    = group * 16 + g;
    const int leng = ilen[b];
    const float* xb = x + (size_t)b * Tt * Nn;
    const unsigned short* wb = w + (size_t)b * Tt * Nn;  // unused if !PRE

    // lds: [2 buf][16 g][136 shorts]; row stride 272B (17*16 -> 16B aligned)
    short* const u0p = lds;                 // buf0
    short* const u1p = lds + 16 * 136;      // buf1

    // E A-frags (row-permuted): ea[mt][kc], lane holds E[32*(g>>2)+4*mt+(g&3)][kc*32+quad*8+jj]
    short8 ea[8][4];
    #pragma unroll
    for (int mt = 0; mt < 8; ++mt) {
        const int jr = 32 * (g >> 2) + 4 * mt + (g & 3);
        const float* tr = trans + (size_t)jr * Nn + quad * 8;
        #pragma unroll
        for (int kc = 0; kc < 4; ++kc) {
            short8 v;
            #pragma unroll
            for (int jj = 0; jj < 8; ++jj) v[jj] = bf16b(__expf(tr[kc * 32 + jj]));
            ea[mt][kc] = v;
        }
    }
    short8 ones;
    #pragma unroll
    for (int jj = 0; jj < 8; ++jj) ones[jj] = (short)0x3F80;  // bf16 1.0

    // u0 = exp(x[0]) into buf0 (c = 0)
    {
        int* wp = (int*)(u0p + (size_t)g * 136 + 32 * quad);
        int dw[16];
        #pragma unroll
        for (int s = 0; s < 8; ++s) {
            float4 xv = *(const float4*)(xb + 32 * quad + 4 * s);
            dw[2 * s]     = (int)pk2(__expf(xv.x), __expf(xv.y));
            dw[2 * s + 1] = (int)pk2(__expf(xv.z), __expf(xv.w));
        }
        ((int4*)wp)[0] = make_int4(dw[0], dw[1], dw[2], dw[3]);
        ((int4*)wp)[1] = make_int4(dw[4], dw[5], dw[6], dw[7]);
        ((int4*)wp)[2] = make_int4(dw[8], dw[9], dw[10], dw[11]);
        ((int4*)wp)[3] = make_int4(dw[12], dw[13], dw[14], dw[15]);
    }

    // prefetch rings (register-resident, compile-time slots, direct-load refill)
    float4 xr[2][8];    // path B: depth 2, slot t&1, 32 f32 (x row)
    short8 wr[4][4];    // path A: depth 4, slot t&3, 32 bf16 (w row)
    if (PRE) {
        #pragma unroll
        for (int s = 1; s <= 4; ++s) {
            const unsigned short* wrow = wb + (size_t)s * Nn + 32 * quad;
            #pragma unroll
            for (int i = 0; i < 4; ++i) wr[s & 3][i] = *(const short8*)(wrow + 8 * i);
        }
    } else {
        #pragma unroll
        for (int s = 1; s <= 2; ++s) {
            const float* xrow = xb + (size_t)s * Nn + 32 * quad;
            #pragma unroll
            for (int i = 0; i < 8; ++i) xr[s & 1][i] = *(const float4*)(xrow + 4 * i);
        }
    }
    float c = 0.0f, m_ren = 1.0f;
    float Sreg = 1.0f, Creg = 0.0f;

#define FSTEP(t_, k_)                                                          \
    {                                                                          \
        const int t = (t_);                                                    \
        /* B frags of u_{t-1} (issue early; lgkm wait is in-wave, no barrier)*/\
        const short* ub = ((((t - 1) & 1) ? u1p : u0p)) + (size_t)g * 136;     \
        short8 bf0 = *(const short8*)(ub + quad * 8);                          \
        short8 bf1 = *(const short8*)(ub + 32 + quad * 8);                     \
        short8 bf2 = *(const short8*)(ub + 64 + quad * 8);                     \
        short8 bf3 = *(const short8*)(ub + 96 + quad * 8);                     \
        /* we[mt][r] = w[t][j]; j = 32quad + 4mt + r (value 4mt+r) */          \
        float we[8][4];                                                        \
        if (PRE) {                                                             \
            _Pragma("unroll")                                                  \
            for (int i = 0; i < 4; ++i) {                                      \
                const unsigned int* wd = (const unsigned int*)&wr[(k_) & 3][i];\
                _Pragma("unroll")                                              \
                for (int dd = 0; dd < 4; ++dd) {                               \
                    const int v = 8 * i + 2 * dd; /* = 4mt+r */                \
                    we[v >> 2][v & 3] = bflo(wd[dd]);                          \
                    we[(v + 1) >> 2][(v + 1) & 3] = bfhi(wd[dd]);              \
                }                                                              \
            }                                                                  \
        } else {                                                               \
            _Pragma("unroll")                                                  \
            for (int i = 0; i < 8; ++i) {                                      \
                float4 v = xr[(k_) & 1][i];                                    \
                we[i][0] = __expf(v.x - D9); we[i][1] = __expf(v.y - D9);      \
                we[i][2] = __expf(v.z - D9); we[i][3] = __expf(v.w - D9);      \
            }                                                                  \
        }                                                                      \
        if ((k_) == 0) { /* renorm apply (measured at prev k==7) */            \
            float invm = 1.0f / m_ren;                                         \
            _Pragma("unroll")                                                  \
            for (int mt = 0; mt < 8; ++mt) {                                   \
                we[mt][0] *= invm; we[mt][1] *= invm;                          \
                we[mt][2] *= invm; we[mt][3] *= invm;                          \
            }                                                                  \
        }                                                                      \
        /* ring refill: direct global->ring-reg, consumed 4(A)/2(B) steps on */\
        if (PRE) {                                                             \
            int rr = t + 4; if (rr > Tt - 1) rr = Tt - 1;                      \
            const unsigned short* wrow = wb + (size_t)rr * Nn + 32 * quad;     \
            _Pragma("unroll")                                                  \
            for (int i = 0; i < 4; ++i) wr[(k_) & 3][i] = *(const short8*)(wrow + 8 * i); \
        } else {                                                               \
            int rr = t + 2; if (rr > Tt - 1) rr = Tt - 1;                      \
            const float* xrow = xb + (size_t)rr * Nn + 32 * quad;              \
            _Pragma("unroll")                                                  \
            for (int i = 0; i < 8; ++i) xr[(k_) & 1][i] = *(const float4*)(xrow + 4 * i); \
        }                                                                      \
        /* 8 m-tiles + sum tile, 4 K-chunks */                                 \
        f32x4 acc[8]; f32x4 accS = {0.f, 0.f, 0.f, 0.f};                       \
        _Pragma("unroll")                                                      \
        for (int mt = 0; mt < 8; ++mt) acc[mt] = (f32x4){0.f, 0.f, 0.f, 0.f};  \
        _Pragma("unroll")                                                      \
        for (int mt = 0; mt < 8; ++mt)                                         \
            acc[mt] = __builtin_amdgcn_mfma_f32_16x16x32_bf16(ea[mt][0], bf0, acc[mt], 0, 0, 0); \
        accS = __builtin_amdgcn_mfma_f32_16x16x32_bf16(ones, bf0, accS, 0, 0, 0); \
        _Pragma("unroll")                                                      \
        for (int mt = 0; mt < 8; ++mt)                                         \
            acc[mt] = __builtin_amdgcn_mfma_f32_16x16x32_bf16(ea[mt][1], bf1, acc[mt], 0, 0, 0); \
        accS = __builtin_amdgcn_mfma_f32_16x16x32_bf16(ones, bf1, accS, 0, 0, 0); \
        _Pragma("unroll")                                                      \
        for (int mt = 0; mt < 8; ++mt)                                         \
            acc[mt] = __builtin_amdgcn_mfma_f32_16x16x32_bf16(ea[mt][2], bf2, acc[mt], 0, 0, 0); \
        accS = __builtin_amdgcn_mfma_f32_16x16x32_bf16(ones, bf2, accS, 0, 0, 0); \
        _Pragma("unroll")                                                      \
        for (int mt = 0; mt < 8; ++mt)                                         \
            acc[mt] = __builtin_amdgcn_mfma_f32_16x16x32_bf16(ea[mt][3], bf3, acc[mt], 0, 0, 0); \
        accS = __builtin_amdgcn_mfma_f32_16x16x32_bf16(ones, bf3, accS, 0, 0, 0); \
        /* snapshot: accS holds colsum(u_{t-1}); capture BEFORE c update */    \
        if (t == leng) { Sreg = accS[0]; Creg = c; }                           \
        if ((k_) == 0) c += __logf(m_ren);                                     \
        /* un = we * acc -> pack bf16 -> 4x ds_write_b128 (contiguous 64B) */  \
        _Pragma("unroll")                                                      \
        for (int mt = 0; mt < 8; ++mt) {                                       \
            we[mt][0] *= acc[mt][0]; we[mt][1] *= acc[mt][1];                  \
            we[mt][2] *= acc[mt][2]; we[mt][3] *= acc[mt][3];                  \
        }                                                                      \
        {                                                                      \
            int* wp = (int*)((((t & 1) ? u1p : u0p)) + (size_t)g * 136 + 32 * quad); \
            int dw[16];                                                        \
            _Pragma("unroll")                                                  \
            for (int mt = 0; mt < 8; ++mt) {                                   \
                dw[2 * mt]     = (int)pk2(we[mt][0], we[mt][1]);               \
                dw[2 * mt + 1] = (int)pk2(we[mt][2], we[mt][3]);               \
            }                                                                  \
            ((int4*)wp)[0] = make_int4(dw[0], dw[1], dw[2], dw[3]);            \
            ((int4*)wp)[1] = make_int4(dw[4], dw[5], dw[6], dw[7]);            \
            ((int4*)wp)[2] = make_int4(dw[8], dw[9], dw[10], dw[11]);          \
            ((int4*)wp)[3] = make_int4(dw[12], dw[13], dw[14], dw[15]);        \
        }                                                                      \
        if ((k_) == 7) { /* renorm measure (wave-wide max of un) */            \
            float mm = we[0][0];                                               \
            _Pragma("unroll")                                                  \
            for (int mt = 0; mt < 8; ++mt) {                                   \
                mm = fmaxf(mm, we[mt][0]); mm = fmaxf(mm, we[mt][1]);          \
                mm = fmaxf(mm, we[mt][2]); mm = fmaxf(mm, we[mt][3]);          \
            }                                                                  \
            mm = fmaxf(mm, __shfl_xor(mm, 1));  mm = fmaxf(mm, __shfl_xor(mm, 2)); \
            mm = fmaxf(mm, __shfl_xor(mm, 4));  mm = fmaxf(mm, __shfl_xor(mm, 8)); \
            mm = fmaxf(mm, __shfl_xor(mm, 16)); mm = fmaxf(mm, __shfl_xor(mm, 32)); \
            m_ren = mm;                                                        \
        }                                                                      \
    }

    // prologue t = 1..7, then chunks t = 8..1023
    #pragma unroll
    for (int k = 1; k < 8; ++k) FSTEP(k, k)
    for (int tb = 8; tb < Tt; tb += 8) {
        #pragma unroll
        for (int k = 0; k < 8; ++k) FSTEP(tb + k, k)
    }
    // tail t = 1024: only the colsum of u_1023 matters (for leng == 1024)
    {
        const short* ub = u1p + (size_t)g * 136;  // buf (1023&1)=1
        short8 bf0 = *(const short8*)(ub + quad * 8);
        short8 bf1 = *(const short8*)(ub + 32 + quad * 8);
        short8 bf2 = *(const short8*)(ub + 64 + quad * 8);
        short8 bf3 = *(const short8*)(ub + 96 + quad * 8);
        f32x4 accS = {0.f, 0.f, 0.f, 0.f};
        accS = __builtin_amdgcn_mfma_f32_16x16x32_bf16(ones, bf0, accS, 0, 0, 0);
        accS = __builtin_amdgcn_mfma_f32_16x16x32_bf16(ones, bf1, accS, 0, 0, 0);
        accS = __builtin_amdgcn_mfma_f32_16x16x32_bf16(ones, bf2, accS, 0, 0, 0);
        accS = __builtin_amdgcn_mfma_f32_16x16x32_bf16(ones, bf3, accS, 0, 0, 0);
        if (leng == Tt) { Sreg = accS[0]; Creg = c; }
    }
#undef FSTEP

    if (quad == 0)
        fcc_out[b] = Creg + __logf(Sreg) + D9 * (float)(leng - 1);
}

// ---- FAC per-step body (unchanged from R6: no barriers, direct-load em ring) ----
#define FAC_STEP(t_, k_)                                                       \
    {                                                                          \
        const int t = (t_);                                                    \
        const int d = ((k_) + 7) & 7;                                          \
        float e0 = em[d][0], e1 = em[d][1], e2 = em[d][2], e3 = em[d][3];      \
        int tn = t + 8; if (tn > Tt - 1) tn = Tt - 1;                          \
        const float* xrow = xb + (size_t)tn * Nn;                              \
        em[d][0] = xrow[tgi[0]]; em[d][1] = xrow[tgi[1]];                      \
        em[d][2] = xrow[tgi[2]]; em[d][3] = xrow[tgi[3]];                      \
        float bup = __shfl_up(bt[3], 1);                                       \
        float prev0 = (lane == 0) ? NEGF : bup;                                \
        float nb[4];                                                           \
        {                                                                      \
            float aa = bt[0] + st[0], bb = prev0 + ntr[0];                     \
            float hi = fmaxf(aa, bb), lo = fminf(aa, bb);                      \
            nb[0] = e0 + hi + __logf(1.0f + __expf(lo - hi));                  \
        }                                                                      \
        {                                                                      \
            float aa = bt[1] + st[1], bb = bt[0] + ntr[1];                     \
            float hi = fmaxf(aa, bb), lo = fminf(aa, bb);                      \
            nb[1] = e1 + hi + __logf(1.0f + __expf(lo - hi));                  \
        }                                                                      \
        {                                                                      \
            float aa = bt[2] + st[2], bb = bt[1] + ntr[2];                     \
            float hi = fmaxf(aa, bb), lo = fminf(aa, bb);                      \
            nb[2] = e2 + hi + __logf(1.0f + __expf(lo - hi));                  \
        }                                                                      \
        {                                                                      \
            float aa = bt[3] + st[3], bb = bt[2] + ntr[3];                     \
            float hi = fmaxf(aa, bb), lo = fminf(aa, bb);                      \
            nb[3] = e3 + hi + __logf(1.0f + __expf(lo - hi));                  \
        }                                                                      \
        if (t < len) {                                                         \
            bt[0] = nb[0]; bt[1] = nb[1]; bt[2] = nb[2]; bt[3] = nb[3];        \
        }                                                                      \
    }

// blocks 0..1: FCC (4 independent single-wave groups each). blocks 2..33: FAC.
template<bool PRE>
__global__ __launch_bounds__(256, 1) void asg_main(
    const float* __restrict__ trans, const float* __restrict__ x,
    const unsigned short* __restrict__ w,
    const int* __restrict__ targets, const int* __restrict__ ilen,
    const int* __restrict__ tlen,
    float* __restrict__ fcc_out, float* __restrict__ fac_out)
{
    __shared__ __align__(16) short uts[4][2][16][136];  // per-group double buffer

    const int tid  = threadIdx.x;
    const int q    = tid >> 6;
    const int lane = tid & 63;

    if (blockIdx.x < 2) {
        const int group = (blockIdx.x << 2) + q;
        fcc_wave<PRE>(trans, x, w, ilen, fcc_out, group, &uts[q][0][0][0], lane);
    } else {
        const int b   = ((blockIdx.x - 2) << 2) + q;
        const int len = ilen[b];
        const int tl  = tlen[b];
        const float* xb = x + (size_t)b * Tt * Nn;

        int   tgi[4];
        float st[4], ntr[4], bt[4];
        #pragma unroll
        for (int r = 0; r < 4; ++r) {
            const int s = (lane << 2) + r;
            const int tgv = targets[b * Ss + s];
            const int pg  = (s == 0) ? tgv : targets[b * Ss + s - 1];
            tgi[r] = tgv;
            st[r]  = trans[tgv * Nn + tgv];
            ntr[r] = trans[tgv * Nn + pg];
            bt[r]  = (s == 0) ? xb[tgv] : NEGF;
        }
        float em[8][4];
        #pragma unroll
        for (int k = 1; k <= 8; ++k) {
            int tt = k; if (tt > Tt - 1) tt = Tt - 1;
            const float* xrow = xb + (size_t)tt * Nn;
            em[(k - 1) & 7][0] = xrow[tgi[0]];
            em[(k - 1) & 7][1] = xrow[tgi[1]];
            em[(k - 1) & 7][2] = xrow[tgi[2]];
            em[(k - 1) & 7][3] = xrow[tgi[3]];
        }
        #pragma unroll
        for (int k = 1; k < 8; ++k) FAC_STEP(k, k)
        for (int tb = 8; tb < Tt; tb += 8) {
            #pragma unroll
            for (int k = 0; k < 8; ++k) FAC_STEP(tb + k, k)
        }
        #pragma unroll
        for (int r = 0; r < 4; ++r)
            if ((lane << 2) + r == tl - 1) fac_out[b] = bt[r];
    }
}

__global__ __launch_bounds__(128) void reduce_kernel(const float* __restrict__ fcc,
                                                     const float* __restrict__ fac,
                                                     float* __restrict__ out) {
    __shared__ float r2[2];
    int tid = threadIdx.x;
    float v = fcc[tid] - fac[tid];
    #pragma unroll
    for (int o = 32; o > 0; o >>= 1) v += __shfl_xor(v, o);
    if ((tid & 63) == 0) r2[tid >> 6] = v;
    __syncthreads();
    if (tid == 0) out[0] = (r2[0] + r2[1]) * (1.0f / Bb);
}

extern "C" void kernel_launch(void* const* d_in, const int* in_sizes, int n_in,
                              void* d_out, int out_size, void* d_ws, size_t ws_size,
                              hipStream_t stream) {
    const float* trans   = (const float*)d_in[0];
    const float* x       = (const float*)d_in[1];
    const int*   targets = (const int*)d_in[2];
    const int*   ilen    = (const int*)d_in[3];
    const int*   tlen    = (const int*)d_in[4];
    float* out = (float*)d_out;

    float* fcc = (float*)d_ws;            // 128 floats
    float* fac = fcc + Bb;                // 128 floats
    const size_t wbytes = (size_t)Bb * Tt * Nn * 2;  // 32 MB bf16
    unsigned short* wbuf = (unsigned short*)((char*)d_ws + 4096);

    if (ws_size >= 4096 + wbytes) {
        wexp_kernel<<<(Bb * Tt * Nn) / (256 * 8), 256, 0, stream>>>(x, wbuf);
        asg_main<true><<<34, 256, 0, stream>>>(trans, x, wbuf, targets, ilen, tlen, fcc, fac);
    } else {
        asg_main<false><<<34, 256, 0, stream>>>(trans, x, wbuf, targets, ilen, tlen, fcc, fac);
    }
    reduce_kernel<<<1, 128, 0, stream>>>(fcc, fac, out);
}

// Round 10
// 547.243 us; speedup vs baseline: 1.6969x; 1.6969x over previous
//
#include <hip/hip_runtime.h>
#include <hip/hip_bf16.h>

#define Bb 128
#define Tt 1024
#define Nn 128
#define Ss 256
#define NEGF (-1e30f)
#define D9 9.0f   // fixed log-domain shift per step; absorbed as D9*(len-1) at the end

typedef __attribute__((ext_vector_type(8))) short short8;  // 8 bf16 = 4 VGPRs (MFMA A/B frag)
typedef __attribute__((ext_vector_type(4))) float f32x4;   // MFMA C/D frag

__device__ __forceinline__ short bf16b(float f) {
    __hip_bfloat16 h = __float2bfloat16(f);
    return *reinterpret_cast<short*>(&h);
}
__device__ __forceinline__ int pk2(float lo, float hi) {
    return (int)(((unsigned int)(unsigned short)bf16b(lo)) |
                 ((unsigned int)(unsigned short)bf16b(hi) << 16));
}

#define MFMA16(A, B, C) __builtin_amdgcn_mfma_f32_16x16x32_bf16((A), (B), (C), 0, 0, 0)

// ---- FCC per-step body (one 16-batch group, 4 waves). t_ = tb + k_, k_ const.
// E row-permuted so lane's 8 outputs are true rows base..base+7 -> 1 ds_write_b128.
// Free-running u + ones-tile colsum + (S,C) snapshot at t==leng (R9-verified).
// Ring: xs[(k+1)&3] holds x[t+1]; consume then refill directly (R6-verified).
#define FCC_STEP(t_, k_)                                                       \
    {                                                                          \
        const int t = (t_);                                                    \
        float mren = 0.0f;                                                     \
        if ((k_) == 0) { /* per-batch renorm apply (measured at prev k==7) */  \
            mren = fmaxf(fmaxf(wredp[0][g], wredp[1][g]),                      \
                         fmaxf(wredp[2][g], wredp[3][g]));                     \
            float invm = 1.0f / mren;                                          \
            wc[0] *= invm; wc[1] *= invm; wc[2] *= invm; wc[3] *= invm;        \
            wc[4] *= invm; wc[5] *= invm; wc[6] *= invm; wc[7] *= invm;        \
        }                                                                      \
        const short* ub = ubuf[(t - 1) & 1] + g * 136 + quad * 8;              \
        short8 bf0 = *(const short8*)(ub);                                     \
        short8 bf1 = *(const short8*)(ub + 32);                                \
        short8 bf2 = *(const short8*)(ub + 64);                                \
        short8 bf3 = *(const short8*)(ub + 96);                                \
        f32x4 a0 = {0.f, 0.f, 0.f, 0.f}, a1 = {0.f, 0.f, 0.f, 0.f};            \
        a0 = MFMA16(ea[0][0], bf0, a0);  a1 = MFMA16(ea[1][0], bf0, a1);       \
        a0 = MFMA16(ea[0][1], bf1, a0);  a1 = MFMA16(ea[1][1], bf1, a1);       \
        a0 = MFMA16(ea[0][2], bf2, a0);  a1 = MFMA16(ea[1][2], bf2, a1);       \
        a0 = MFMA16(ea[0][3], bf3, a0);  a1 = MFMA16(ea[1][3], bf3, a1);       \
        if (q == 0) { /* colsum(u_{t-1}) via ones-tile; snapshot BEFORE c+= */ \
            f32x4 aS = {0.f, 0.f, 0.f, 0.f};                                   \
            aS = MFMA16(ones, bf0, aS);  aS = MFMA16(ones, bf1, aS);           \
            aS = MFMA16(ones, bf2, aS);  aS = MFMA16(ones, bf3, aS);           \
            if (t == leng) { Sreg = aS[0]; Creg = c; }                         \
        }                                                                      \
        if ((k_) == 0) c += __logf(mren);                                      \
        float un[8];                                                           \
        un[0] = wc[0] * a0[0]; un[1] = wc[1] * a0[1];                          \
        un[2] = wc[2] * a0[2]; un[3] = wc[3] * a0[3];                          \
        un[4] = wc[4] * a1[0]; un[5] = wc[5] * a1[1];                          \
        un[6] = wc[6] * a1[2]; un[7] = wc[7] * a1[3];                          \
        {                                                                      \
            int4 dw;                                                           \
            dw.x = pk2(un[0], un[1]); dw.y = pk2(un[2], un[3]);                \
            dw.z = pk2(un[4], un[5]); dw.w = pk2(un[6], un[7]);                \
            *(int4*)(ubuf[t & 1] + g * 136 + base) = dw;                       \
        }                                                                      \
        const int sl = ((k_) + 1) & 3;                                         \
        wc[0] = __expf(xs[sl][0].x - D9); wc[1] = __expf(xs[sl][0].y - D9);    \
        wc[2] = __expf(xs[sl][0].z - D9); wc[3] = __expf(xs[sl][0].w - D9);    \
        wc[4] = __expf(xs[sl][1].x - D9); wc[5] = __expf(xs[sl][1].y - D9);    \
        wc[6] = __expf(xs[sl][1].z - D9); wc[7] = __expf(xs[sl][1].w - D9);    \
        {                                                                      \
            int kk = t + 5; if (kk > Tt - 1) kk = Tt - 1;                      \
            const float* xr_ = xb + (size_t)kk * Nn + base;                    \
            xs[sl][0] = *(const float4*)(xr_);                                 \
            xs[sl][1] = *(const float4*)(xr_ + 4);                             \
        }                                                                      \
        if ((k_) == 7) { /* renorm measure: per-batch max over this step's u */\
            float mm = un[0];                                                  \
            mm = fmaxf(mm, un[1]); mm = fmaxf(mm, un[2]); mm = fmaxf(mm, un[3]); \
            mm = fmaxf(mm, un[4]); mm = fmaxf(mm, un[5]); mm = fmaxf(mm, un[6]); \
            mm = fmaxf(mm, un[7]);                                             \
            mm = fmaxf(mm, __shfl_xor(mm, 16));                                \
            mm = fmaxf(mm, __shfl_xor(mm, 32));                                \
            if (lane < 16) wredp[q][lane] = mm;                                \
        }                                                                      \
        __syncthreads();                                                       \
    }

// ---- FAC per-step body (R6-verified: no barriers, direct-load em ring) ----
#define FAC_STEP(t_, k_)                                                       \
    {                                                                          \
        const int t = (t_);                                                    \
        const int d = ((k_) + 7) & 7;                                          \
        float e0 = em[d][0], e1 = em[d][1], e2 = em[d][2], e3 = em[d][3];      \
        int tn = t + 8; if (tn > Tt - 1) tn = Tt - 1;                          \
        const float* xrow = xb + (size_t)tn * Nn;                              \
        em[d][0] = xrow[tgi[0]]; em[d][1] = xrow[tgi[1]];                      \
        em[d][2] = xrow[tgi[2]]; em[d][3] = xrow[tgi[3]];                      \
        float bup = __shfl_up(bt[3], 1);                                       \
        float prev0 = (lane == 0) ? NEGF : bup;                                \
        float nb[4];                                                           \
        {                                                                      \
            float aa = bt[0] + st[0], bb = prev0 + ntr[0];                     \
            float hi = fmaxf(aa, bb), lo = fminf(aa, bb);                      \
            nb[0] = e0 + hi + __logf(1.0f + __expf(lo - hi));                  \
        }                                                                      \
        {                                                                      \
            float aa = bt[1] + st[1], bb = bt[0] + ntr[1];                     \
            float hi = fmaxf(aa, bb), lo = fminf(aa, bb);                      \
            nb[1] = e1 + hi + __logf(1.0f + __expf(lo - hi));                  \
        }                                                                      \
        {                                                                      \
            float aa = bt[2] + st[2], bb = bt[1] + ntr[2];                     \
            float hi = fmaxf(aa, bb), lo = fminf(aa, bb);                      \
            nb[2] = e2 + hi + __logf(1.0f + __expf(lo - hi));                  \
        }                                                                      \
        {                                                                      \
            float aa = bt[3] + st[3], bb = bt[2] + ntr[3];                     \
            float hi = fmaxf(aa, bb), lo = fminf(aa, bb);                      \
            nb[3] = e3 + hi + __logf(1.0f + __expf(lo - hi));                  \
        }                                                                      \
        if (t < len) {                                                         \
            bt[0] = nb[0]; bt[1] = nb[1]; bt[2] = nb[2]; bt[3] = nb[3];        \
        }                                                                      \
    }

// 512-thread blocks (8 waves -> 2 waves/SIMD: cross-group latency hiding).
// blocks 0..3:  FCC, TWO 16-batch groups each (waves 0-3 / 4-7).
// blocks 4..19: FAC, 8 batches each (1 wave per batch).
__global__ __launch_bounds__(512, 2) void asg_main(
    const float* __restrict__ trans, const float* __restrict__ x,
    const int* __restrict__ targets, const int* __restrict__ ilen,
    const int* __restrict__ tlen,
    float* __restrict__ fcc_out, float* __restrict__ fac_out)
{
    __shared__ __align__(16) short uts[2][2][16][136];  // [grp][buf][g][j], row 272B
    __shared__ float wred[2][4][16];

    const int tid  = threadIdx.x;
    const int q8   = tid >> 6;      // wave 0..7
    const int lane = tid & 63;

    if (blockIdx.x < 4) {
        // ================= FCC =================
        const int grp  = q8 >> 2;       // group-in-block
        const int q    = q8 & 3;        // wave-in-group
        const int g    = lane & 15;     // batch col
        const int quad = lane >> 4;
        const int base = 32 * q + 8 * quad;  // this lane's 8 contiguous true rows
        const int group = (blockIdx.x << 1) + grp;
        const int b    = group * 16 + g;
        const int leng = ilen[b];
        const float* xb = x + (size_t)b * Tt * Nn;

        short* ubuf[2] = { &uts[grp][0][0][0], &uts[grp][1][0][0] };
        float (*wredp)[16] = wred[grp];

        // E A-frags, row-permuted: tile mt covers true rows 32q+8*(g>>2)+4mt+(g&3)
        short8 ea[2][4];
        #pragma unroll
        for (int mt = 0; mt < 2; ++mt) {
            const int jr = 32 * q + 8 * (g >> 2) + 4 * mt + (g & 3);
            const float* tr = trans + (size_t)jr * Nn + quad * 8;
            #pragma unroll
            for (int kc = 0; kc < 4; ++kc) {
                short8 v;
                #pragma unroll
                for (int jj = 0; jj < 8; ++jj) v[jj] = bf16b(__expf(tr[kc * 32 + jj]));
                ea[mt][kc] = v;
            }
        }
        short8 ones;
        #pragma unroll
        for (int jj = 0; jj < 8; ++jj) ones[jj] = (short)0x3F80;  // bf16 1.0

        // u0 = exp(x[0]) -> buf0 (c = 0); each lane writes its 8 rows of batch g
        {
            const float* x0 = xb + base;
            int4 dw;
            dw.x = pk2(__expf(x0[0]), __expf(x0[1]));
            dw.y = pk2(__expf(x0[2]), __expf(x0[3]));
            dw.z = pk2(__expf(x0[4]), __expf(x0[5]));
            dw.w = pk2(__expf(x0[6]), __expf(x0[7]));
            *(int4*)(ubuf[0] + g * 136 + base) = dw;
        }

        // wc = exp(x[1]-D9) for step 1; ring xs[k&3] = x[k], k=2..5
        float wc[8];
        float4 xs[4][2];
        {
            const float* x1 = xb + Nn + base;
            #pragma unroll
            for (int i = 0; i < 8; ++i) wc[i] = __expf(x1[i] - D9);
            #pragma unroll
            for (int k = 2; k <= 5; ++k) {
                const float* xr_ = xb + (size_t)k * Nn + base;
                xs[k & 3][0] = *(const float4*)(xr_);
                xs[k & 3][1] = *(const float4*)(xr_ + 4);
            }
        }
        float c = 0.0f, Sreg = 1.0f, Creg = 0.0f;
        __syncthreads();

        #pragma unroll
        for (int k = 1; k < 8; ++k) FCC_STEP(k, k)
        for (int tb = 8; tb < Tt; tb += 8) {
            #pragma unroll
            for (int k = 0; k < 8; ++k) FCC_STEP(tb + k, k)
        }

        // tail t = 1024: colsum(u_1023) for leng == Tt
        if (q == 0) {
            const short* ub = ubuf[1] + g * 136 + quad * 8;  // 1023 & 1 == 1
            short8 bf0 = *(const short8*)(ub);
            short8 bf1 = *(const short8*)(ub + 32);
            short8 bf2 = *(const short8*)(ub + 64);
            short8 bf3 = *(const short8*)(ub + 96);
            f32x4 aS = {0.f, 0.f, 0.f, 0.f};
            aS = MFMA16(ones, bf0, aS);  aS = MFMA16(ones, bf1, aS);
            aS = MFMA16(ones, bf2, aS);  aS = MFMA16(ones, bf3, aS);
            if (leng == Tt) { Sreg = aS[0]; Creg = c; }
            if (quad == 0)
                fcc_out[b] = Creg + __logf(Sreg) + D9 * (float)(leng - 1);
        }
    } else {
        // ================= FAC (1 wave per batch, no barriers) =================
        const int b   = ((blockIdx.x - 4) << 3) + q8;
        const int len = ilen[b];
        const int tl  = tlen[b];
        const float* xb = x + (size_t)b * Tt * Nn;

        int   tgi[4];
        float st[4], ntr[4], bt[4];
        #pragma unroll
        for (int r = 0; r < 4; ++r) {
            const int s = (lane << 2) + r;
            const int tgv = targets[b * Ss + s];
            const int pg  = (s == 0) ? tgv : targets[b * Ss + s - 1];
            tgi[r] = tgv;
            st[r]  = trans[tgv * Nn + tgv];
            ntr[r] = trans[tgv * Nn + pg];
            bt[r]  = (s == 0) ? xb[tgv] : NEGF;
        }
        float em[8][4];
        #pragma unroll
        for (int k = 1; k <= 8; ++k) {
            int tt = k; if (tt > Tt - 1) tt = Tt - 1;
            const float* xrow = xb + (size_t)tt * Nn;
            em[(k - 1) & 7][0] = xrow[tgi[0]];
            em[(k - 1) & 7][1] = xrow[tgi[1]];
            em[(k - 1) & 7][2] = xrow[tgi[2]];
            em[(k - 1) & 7][3] = xrow[tgi[3]];
        }
        #pragma unroll
        for (int k = 1; k < 8; ++k) FAC_STEP(k, k)
        for (int tb = 8; tb < Tt; tb += 8) {
            #pragma unroll
            for (int k = 0; k < 8; ++k) FAC_STEP(tb + k, k)
        }
        #pragma unroll
        for (int r = 0; r < 4; ++r)
            if ((lane << 2) + r == tl - 1) fac_out[b] = bt[r];
    }
}

__global__ __launch_bounds__(128) void reduce_kernel(const float* __restrict__ fcc,
                                                     const float* __restrict__ fac,
                                                     float* __restrict__ out) {
    __shared__ float r2[2];
    int tid = threadIdx.x;
    float v = fcc[tid] - fac[tid];
    #pragma unroll
    for (int o = 32; o > 0; o >>= 1) v += __shfl_xor(v, o);
    if ((tid & 63) == 0) r2[tid >> 6] = v;
    __syncthreads();
    if (tid == 0) out[0] = (r2[0] + r2[1]) * (1.0f / Bb);
}

extern "C" void kernel_launch(void* const* d_in, const int* in_sizes, int n_in,
                              void* d_out, int out_size, void* d_ws, size_t ws_size,
                              hipStream_t stream) {
    const float* trans   = (const float*)d_in[0];
    const float* x       = (const float*)d_in[1];
    const int*   targets = (const int*)d_in[2];
    const int*   ilen    = (const int*)d_in[3];
    const int*   tlen    = (const int*)d_in[4];
    float* out = (float*)d_out;

    float* fcc = (float*)d_ws;       // 128 floats
    float* fac = fcc + Bb;           // 128 floats

    asg_main<<<20, 512, 0, stream>>>(trans, x, targets, ilen, tlen, fcc, fac);
    reduce_kernel<<<1, 128, 0, stream>>>(fcc, fac, out);
}